// Round 1
// baseline (731.334 us; speedup 1.0000x reference)
//
#include <hip/hip_runtime.h>
#include <hip/hip_bf16.h>

#define B_SZ 2
#define H_SZ 16
#define S_SZ 2048
#define D_SZ 64
#define QT   16          // q-rows per workgroup
#define WAVES 8
#define KPW  256         // k-cols per wave (S / WAVES)
#define NCB  16          // 16-col blocks per wave

typedef __bf16 bf16x8 __attribute__((ext_vector_type(8)));
typedef float  f32x4  __attribute__((ext_vector_type(4)));

// One workgroup = one (b,h) x 16 q-rows. 8 waves, wave w owns k-cols [256w,256w+256).
// QK^T swapped (A=K, B=Q) so each lane holds one q-row (lane&15) and 4 k-cols per
// 16x16 fragment: s[cb][r] = S[q0+(lane&15)][kbase+16cb+4g+r], g=lane>>4.
// bf16 hi/lo split (3 MFMA) gives ~fp32-accurate scores.
// PV reuses s[] directly as the A-fragment via the k-permutation
// kk=8g+j -> (j<4 ? 4g+j : 16+4g+j-4), applied equally to the V B-fragment.
__global__ __launch_bounds__(512) void attn_fused(
    const float* __restrict__ Q, const float* __restrict__ K,
    const float* __restrict__ V, float* __restrict__ OutC,
    float* __restrict__ OutW)
{
    __shared__ float redm[WAVES][QT];
    __shared__ float reds[WAVES][QT];
    __shared__ float ctxred[WAVES][QT][D_SZ];   // 32 KB

    const int tid  = threadIdx.x;
    const int lane = tid & 63;
    const int wv   = tid >> 6;
    const int l15  = lane & 15;
    const int g    = lane >> 4;

    const int wg = blockIdx.x;
    const int bh = wg >> 7;           // 128 q-tiles per (b,h)
    const int qt = wg & 127;
    const int q0 = qt * QT;

    const float* Qb = Q + (size_t)bh * S_SZ * D_SZ;
    const float* Kb = K + (size_t)bh * S_SZ * D_SZ;
    const float* Vb = V + (size_t)bh * S_SZ * D_SZ;
    float* Wb = OutW + (size_t)bh * S_SZ * S_SZ;
    float* Cb = OutC + (size_t)bh * S_SZ * D_SZ;

    // ---- Q fragments (B operand): lane holds Q[q0+l15][8g + 32ks + j], j=0..7
    bf16x8 qhi[2], qlo[2];
    {
        const float* qp = Qb + (size_t)(q0 + l15) * D_SZ + 8 * g;
        #pragma unroll
        for (int ks = 0; ks < 2; ++ks) {
            f32x4 a = *(const f32x4*)(qp + 32 * ks);
            f32x4 b = *(const f32x4*)(qp + 32 * ks + 4);
            #pragma unroll
            for (int j = 0; j < 4; ++j) {
                __bf16 h0 = (__bf16)a[j];
                __bf16 h1 = (__bf16)b[j];
                qhi[ks][j]     = h0;
                qhi[ks][4 + j] = h1;
                qlo[ks][j]     = (__bf16)(a[j] - (float)h0);
                qlo[ks][4 + j] = (__bf16)(b[j] - (float)h1);
            }
        }
    }

    const int kbase = wv * KPW;

    // ---- QK^T: 16 col-blocks, K=64 as 2 k-steps, 3-term bf16 split
    f32x4 s[NCB];
    #pragma unroll
    for (int cb = 0; cb < NCB; ++cb) {
        f32x4 acc = {0.f, 0.f, 0.f, 0.f};
        const float* kp = Kb + (size_t)(kbase + cb * 16 + l15) * D_SZ + 8 * g;
        #pragma unroll
        for (int ks = 0; ks < 2; ++ks) {
            f32x4 a = *(const f32x4*)(kp + 32 * ks);
            f32x4 b = *(const f32x4*)(kp + 32 * ks + 4);
            bf16x8 khi, klo;
            #pragma unroll
            for (int j = 0; j < 4; ++j) {
                __bf16 h0 = (__bf16)a[j];
                __bf16 h1 = (__bf16)b[j];
                khi[j]     = h0;
                khi[4 + j] = h1;
                klo[j]     = (__bf16)(a[j] - (float)h0);
                klo[4 + j] = (__bf16)(b[j] - (float)h1);
            }
            acc = __builtin_amdgcn_mfma_f32_16x16x32_bf16(khi, qhi[ks], acc, 0, 0, 0);
            acc = __builtin_amdgcn_mfma_f32_16x16x32_bf16(khi, qlo[ks], acc, 0, 0, 0);
            acc = __builtin_amdgcn_mfma_f32_16x16x32_bf16(klo, qhi[ks], acc, 0, 0, 0);
        }
        s[cb] = acc;
    }

    // ---- row max (per-lane 64 -> 4 lanes same row -> 8 waves via LDS)
    float m = -3.0e38f;
    #pragma unroll
    for (int cb = 0; cb < NCB; ++cb) {
        #pragma unroll
        for (int r = 0; r < 4; ++r) m = fmaxf(m, s[cb][r]);
    }
    m = fmaxf(m, __shfl_xor(m, 16));
    m = fmaxf(m, __shfl_xor(m, 32));
    if (lane < 16) redm[wv][l15] = m;
    __syncthreads();
    float mall = redm[0][l15];
    #pragma unroll
    for (int w2 = 1; w2 < WAVES; ++w2) mall = fmaxf(mall, redm[w2][l15]);

    // ---- exp + row sum
    float sm = 0.f;
    #pragma unroll
    for (int cb = 0; cb < NCB; ++cb) {
        #pragma unroll
        for (int r = 0; r < 4; ++r) {
            float e = __expf(s[cb][r] - mall);
            s[cb][r] = e;
            sm += e;
        }
    }
    sm += __shfl_xor(sm, 16);
    sm += __shfl_xor(sm, 32);
    if (lane < 16) reds[wv][l15] = sm;
    __syncthreads();
    float lsum = 0.f;
    #pragma unroll
    for (int w2 = 0; w2 < WAVES; ++w2) lsum += reds[w2][l15];
    const float inv = 1.0f / lsum;

    // ---- normalize, write weights (fp32, float4, 64B/row per instr)
    float* wrow = Wb + (size_t)(q0 + l15) * S_SZ + kbase;
    #pragma unroll
    for (int cb = 0; cb < NCB; ++cb) {
        f32x4 wvec;
        #pragma unroll
        for (int r = 0; r < 4; ++r) wvec[r] = s[cb][r] * inv;
        s[cb] = wvec;
        *(f32x4*)(wrow + cb * 16 + 4 * g) = wvec;
    }

    // ---- PV: A = P (direct from s[] via permutation), B = V (permuted rows)
    f32x4 ctx[4];
    #pragma unroll
    for (int db = 0; db < 4; ++db) ctx[db] = (f32x4){0.f, 0.f, 0.f, 0.f};

    #pragma unroll
    for (int u = 0; u < 8; ++u) {
        bf16x8 pa;
        #pragma unroll
        for (int r = 0; r < 4; ++r) {
            pa[r]     = (__bf16)s[2 * u][r];
            pa[4 + r] = (__bf16)s[2 * u + 1][r];
        }
        const float* vp = Vb + (size_t)(kbase + 32 * u + 4 * g) * D_SZ + l15;
        #pragma unroll
        for (int db = 0; db < 4; ++db) {
            bf16x8 vb;
            #pragma unroll
            for (int j = 0; j < 4; ++j) {
                vb[j]     = (__bf16)vp[(size_t)j * D_SZ + 16 * db];
                vb[4 + j] = (__bf16)vp[(size_t)(16 + j) * D_SZ + 16 * db];
            }
            ctx[db] = __builtin_amdgcn_mfma_f32_16x16x32_bf16(pa, vb, ctx[db], 0, 0, 0);
        }
    }

    // ---- cross-wave context reduction: ctx[db][r] = C[4g+r][l15+16db] (partial)
    #pragma unroll
    for (int db = 0; db < 4; ++db) {
        #pragma unroll
        for (int r = 0; r < 4; ++r)
            ctxred[wv][4 * g + r][16 * db + l15] = ctx[db][r];
    }
    __syncthreads();

    {
        const int qr = tid >> 6;      // 0..7
        const int d  = tid & 63;
        float acc0 = 0.f, acc1 = 0.f;
        #pragma unroll
        for (int w2 = 0; w2 < WAVES; ++w2) {
            acc0 += ctxred[w2][qr][d];
            acc1 += ctxred[w2][qr + 8][d];
        }
        Cb[(size_t)(q0 + qr) * D_SZ + d]     = acc0;
        Cb[(size_t)(q0 + qr + 8) * D_SZ + d] = acc1;
    }
}

extern "C" void kernel_launch(void* const* d_in, const int* in_sizes, int n_in,
                              void* d_out, int out_size, void* d_ws, size_t ws_size,
                              hipStream_t stream)
{
    const float* Q = (const float*)d_in[0];
    const float* K = (const float*)d_in[1];
    const float* V = (const float*)d_in[2];
    float* ctx = (float*)d_out;
    float* w   = (float*)d_out + (size_t)B_SZ * H_SZ * S_SZ * D_SZ;
    dim3 grid(B_SZ * H_SZ * (S_SZ / QT));   // 4096 workgroups
    attn_fused<<<grid, 512, 0, stream>>>(Q, K, V, ctx, w);
}

// Round 2
// 292.634 us; speedup vs baseline: 2.4991x; 2.4991x over previous
//
#include <hip/hip_runtime.h>
#include <hip/hip_bf16.h>

#define B_SZ 2
#define H_SZ 16
#define S_SZ 2048
#define D_SZ 64
#define QT   16
#define WAVES 8
#define NBH  (B_SZ * H_SZ)      // 32
#define NQB  (S_SZ / 16)        // 128 16-row blocks
#define NUB  (S_SZ / 32)        // 64 32-row V blocks

typedef __bf16 bf16x8 __attribute__((ext_vector_type(8)));
typedef float  f32x4  __attribute__((ext_vector_type(4)));

// d_ws layout (bytes): pre-swizzled bf16 MFMA fragments
//  QHI [bh][qb][ks][lane] 16B  : 32*128*2*64*16 = 8 MB
//  QLO  same                   : 8 MB
//  KHI  same                   : 8 MB
//  KLO  same                   : 8 MB
//  VSW [bh][u][db][lane] 16B   : 32*64*4*64*16 = 8 MB   (pi-permuted rows)
#define SEG   (8u * 1024u * 1024u)
#define QHI_OFF (0 * (size_t)SEG)
#define QLO_OFF (1 * (size_t)SEG)
#define KHI_OFF (2 * (size_t)SEG)
#define KLO_OFF (3 * (size_t)SEG)
#define VSW_OFF (4 * (size_t)SEG)

// ---- prep Q/K: fp32 -> bf16 hi/lo, swizzled to A/B fragment order.
// wave-task wid: tensor = wid>>12 (0=Q,1=K), bh = (wid>>7)&31, blk = wid&127
__global__ __launch_bounds__(256) void prep_qk(
    const float* __restrict__ Q, const float* __restrict__ K,
    char* __restrict__ ws)
{
    const int lane = threadIdx.x & 63;
    const int wv   = threadIdx.x >> 6;
    const int l15  = lane & 15;
    const int g    = lane >> 4;
    const int wid  = blockIdx.x * 4 + wv;          // 0..8191
    const int tensor = wid >> 12;
    const int rem  = wid & 4095;
    const int bh   = rem >> 7;
    const int blk  = rem & 127;

    const float* src = (tensor ? K : Q) + ((size_t)bh * S_SZ + blk * 16 + l15) * D_SZ;
    bf16x8* hi = (bf16x8*)(ws + (tensor ? KHI_OFF : QHI_OFF));
    bf16x8* lo = (bf16x8*)(ws + (tensor ? KLO_OFF : QLO_OFF));

    #pragma unroll
    for (int ks = 0; ks < 2; ++ks) {
        const float* p = src + 32 * ks + 8 * g;
        f32x4 a = *(const f32x4*)p;
        f32x4 b = *(const f32x4*)(p + 4);
        bf16x8 vh, vl;
        #pragma unroll
        for (int j = 0; j < 4; ++j) {
            __bf16 h0 = (__bf16)a[j];
            __bf16 h1 = (__bf16)b[j];
            vh[j]     = h0;
            vh[4 + j] = h1;
            vl[j]     = (__bf16)(a[j] - (float)h0);
            vl[4 + j] = (__bf16)(b[j] - (float)h1);
        }
        size_t di = ((size_t)(bh * NQB + blk) * 2 + ks) * 64 + lane;
        hi[di] = vh;
        lo[di] = vl;
    }
}

// ---- prep V: fp32 -> bf16, B-fragment order with pi-permutation baked in.
// wave-task wid: bh = wid>>6, u = wid&63 (32-row block)
__global__ __launch_bounds__(256) void prep_v(
    const float* __restrict__ V, char* __restrict__ ws)
{
    __shared__ float vt[4][32 * 68];
    const int lane = threadIdx.x & 63;
    const int wv   = threadIdx.x >> 6;
    const int l15  = lane & 15;
    const int g    = lane >> 4;
    const int wid  = blockIdx.x * 4 + wv;          // 0..2047
    const int bh   = wid >> 6;
    const int u    = wid & 63;

    const float* src = V + ((size_t)bh * S_SZ + u * 32) * D_SZ;
    float* t = vt[wv];
    #pragma unroll
    for (int i = 0; i < 8; ++i) {
        int idx = i * 64 + lane;       // 512 f32x4 units = 32 rows x 16
        int row = idx >> 4;
        int c4  = idx & 15;
        *(f32x4*)(t + row * 68 + c4 * 4) = *(const f32x4*)(src + row * 64 + c4 * 4);
    }
    __syncthreads();

    bf16x8* vsw = (bf16x8*)(ws + VSW_OFF);
    #pragma unroll
    for (int db = 0; db < 4; ++db) {
        bf16x8 vb;
        #pragma unroll
        for (int j = 0; j < 8; ++j) {
            int kk = (j < 4) ? (4 * g + j) : (16 + 4 * g + (j - 4));
            vb[j] = (__bf16)t[kk * 68 + 16 * db + l15];
        }
        vsw[((size_t)(bh * NUB + u) * 4 + db) * 64 + lane] = vb;
    }
}

// ---- main fused kernel: all operand loads are coalesced dwordx4 in fragment order.
__global__ __launch_bounds__(512) void attn_fused2(
    const char* __restrict__ ws, float* __restrict__ OutC, float* __restrict__ OutW)
{
    __shared__ float redm[WAVES][QT];
    __shared__ float reds[WAVES][QT];
    __shared__ float ctxred[WAVES][QT][D_SZ];

    const int tid  = threadIdx.x;
    const int lane = tid & 63;
    const int wv   = tid >> 6;
    const int l15  = lane & 15;
    const int g    = lane >> 4;

    // XCD-aware swizzle: XCD x gets contiguous work chunk -> same (b,h) K/V in one L2
    const int b    = blockIdx.x;
    const int work = (b & 7) * 512 + (b >> 3);
    const int bh   = work >> 7;
    const int qt   = work & 127;
    const int q0   = qt * QT;

    const bf16x8* QHI = (const bf16x8*)(ws + QHI_OFF);
    const bf16x8* QLO = (const bf16x8*)(ws + QLO_OFF);
    const bf16x8* KHI = (const bf16x8*)(ws + KHI_OFF);
    const bf16x8* KLO = (const bf16x8*)(ws + KLO_OFF);
    const bf16x8* VSW = (const bf16x8*)(ws + VSW_OFF);

    float* Wb = OutW + (size_t)bh * S_SZ * S_SZ;
    float* Cb = OutC + (size_t)bh * S_SZ * D_SZ;

    // Q fragments
    bf16x8 qhi[2], qlo[2];
    {
        size_t qi = ((size_t)(bh * NQB + qt) * 2) * 64 + lane;
        qhi[0] = QHI[qi];       qhi[1] = QHI[qi + 64];
        qlo[0] = QLO[qi];       qlo[1] = QLO[qi + 64];
    }

    // QK^T: 16 col-blocks per wave, 6 MFMA each (3-term bf16 split)
    f32x4 s[16];
    const int kb0 = wv * 16;
    #pragma unroll
    for (int cb = 0; cb < 16; ++cb) {
        size_t bi = ((size_t)(bh * NQB + kb0 + cb) * 2) * 64 + lane;
        bf16x8 kh0 = KHI[bi], kh1 = KHI[bi + 64];
        bf16x8 kl0 = KLO[bi], kl1 = KLO[bi + 64];
        f32x4 acc = {0.f, 0.f, 0.f, 0.f};
        acc = __builtin_amdgcn_mfma_f32_16x16x32_bf16(kh0, qhi[0], acc, 0, 0, 0);
        acc = __builtin_amdgcn_mfma_f32_16x16x32_bf16(kh0, qlo[0], acc, 0, 0, 0);
        acc = __builtin_amdgcn_mfma_f32_16x16x32_bf16(kl0, qhi[0], acc, 0, 0, 0);
        acc = __builtin_amdgcn_mfma_f32_16x16x32_bf16(kh1, qhi[1], acc, 0, 0, 0);
        acc = __builtin_amdgcn_mfma_f32_16x16x32_bf16(kh1, qlo[1], acc, 0, 0, 0);
        acc = __builtin_amdgcn_mfma_f32_16x16x32_bf16(kl1, qhi[1], acc, 0, 0, 0);
        s[cb] = acc;
    }

    // row max: 4 lanes/row in wave -> 8 waves via LDS
    float m = -3.0e38f;
    #pragma unroll
    for (int cb = 0; cb < 16; ++cb) {
        #pragma unroll
        for (int r = 0; r < 4; ++r) m = fmaxf(m, s[cb][r]);
    }
    m = fmaxf(m, __shfl_xor(m, 16));
    m = fmaxf(m, __shfl_xor(m, 32));
    if (lane < 16) redm[wv][l15] = m;
    __syncthreads();
    float mall = redm[0][l15];
    #pragma unroll
    for (int w2 = 1; w2 < WAVES; ++w2) mall = fmaxf(mall, redm[w2][l15]);

    // exp + row sum
    float sm = 0.f;
    #pragma unroll
    for (int cb = 0; cb < 16; ++cb) {
        #pragma unroll
        for (int r = 0; r < 4; ++r) {
            float e = __expf(s[cb][r] - mall);
            s[cb][r] = e;
            sm += e;
        }
    }
    sm += __shfl_xor(sm, 16);
    sm += __shfl_xor(sm, 32);
    if (lane < 16) reds[wv][l15] = sm;
    __syncthreads();
    float lsum = 0.f;
    #pragma unroll
    for (int w2 = 0; w2 < WAVES; ++w2) lsum += reds[w2][l15];
    const float inv = 1.0f / lsum;

    // normalize + write weights
    float* wrow = Wb + (size_t)(q0 + l15) * S_SZ + wv * 256;
    #pragma unroll
    for (int cb = 0; cb < 16; ++cb) {
        f32x4 wvec;
        #pragma unroll
        for (int r = 0; r < 4; ++r) wvec[r] = s[cb][r] * inv;
        s[cb] = wvec;
        *(f32x4*)(wrow + cb * 16 + 4 * g) = wvec;
    }

    // PV: A = P direct from s[], B = pre-permuted V fragments (single dwordx4 each)
    f32x4 ctx[4];
    #pragma unroll
    for (int db = 0; db < 4; ++db) ctx[db] = (f32x4){0.f, 0.f, 0.f, 0.f};

    #pragma unroll
    for (int u = 0; u < 8; ++u) {
        bf16x8 pa;
        #pragma unroll
        for (int r = 0; r < 4; ++r) {
            pa[r]     = (__bf16)s[2 * u][r];
            pa[4 + r] = (__bf16)s[2 * u + 1][r];
        }
        size_t vbase = ((size_t)(bh * NUB + wv * 8 + u) * 4) * 64 + lane;
        #pragma unroll
        for (int db = 0; db < 4; ++db) {
            bf16x8 vb = VSW[vbase + (size_t)db * 64];
            ctx[db] = __builtin_amdgcn_mfma_f32_16x16x32_bf16(pa, vb, ctx[db], 0, 0, 0);
        }
    }

    // cross-wave context reduction
    #pragma unroll
    for (int db = 0; db < 4; ++db) {
        #pragma unroll
        for (int r = 0; r < 4; ++r)
            ctxred[wv][4 * g + r][16 * db + l15] = ctx[db][r];
    }
    __syncthreads();
    {
        const int qr = tid >> 6;
        const int d  = tid & 63;
        float acc0 = 0.f, acc1 = 0.f;
        #pragma unroll
        for (int w2 = 0; w2 < WAVES; ++w2) {
            acc0 += ctxred[w2][qr][d];
            acc1 += ctxred[w2][qr + 8][d];
        }
        Cb[(size_t)(q0 + qr) * D_SZ + d]     = acc0;
        Cb[(size_t)(q0 + qr + 8) * D_SZ + d] = acc1;
    }
}

extern "C" void kernel_launch(void* const* d_in, const int* in_sizes, int n_in,
                              void* d_out, int out_size, void* d_ws, size_t ws_size,
                              hipStream_t stream)
{
    const float* Q = (const float*)d_in[0];
    const float* K = (const float*)d_in[1];
    const float* V = (const float*)d_in[2];
    float* ctx = (float*)d_out;
    float* w   = (float*)d_out + (size_t)B_SZ * H_SZ * S_SZ * D_SZ;
    char*  ws  = (char*)d_ws;

    prep_qk<<<2048, 256, 0, stream>>>(Q, K, ws);
    prep_v <<<512,  256, 0, stream>>>(V, ws);
    attn_fused2<<<4096, 512, 0, stream>>>(ws, ctx, w);
}

// Round 3
// 218.957 us; speedup vs baseline: 3.3401x; 1.3365x over previous
//
#include <hip/hip_runtime.h>
#include <hip/hip_bf16.h>

#define B_SZ 2
#define H_SZ 16
#define S_SZ 2048
#define D_SZ 64
#define QT   16
#define WAVES 8
#define NBH  (B_SZ * H_SZ)      // 32
#define NQB  (S_SZ / 16)        // 128 16-row blocks
#define NUB  (S_SZ / 32)        // 64 32-row V blocks

typedef __bf16 bf16x8 __attribute__((ext_vector_type(8)));
typedef float  f32x4  __attribute__((ext_vector_type(4)));

// d_ws layout (bytes): pre-swizzled bf16 MFMA fragments
//  QHI [bh][qb][ks][lane] 16B  : 8 MB   QLO / KHI / KLO same
//  VSW [bh][u][db][lane] 16B   : 8 MB   (pi-permuted rows)
#define SEG   (8u * 1024u * 1024u)
#define QHI_OFF (0 * (size_t)SEG)
#define QLO_OFF (1 * (size_t)SEG)
#define KHI_OFF (2 * (size_t)SEG)
#define KLO_OFF (3 * (size_t)SEG)
#define VSW_OFF (4 * (size_t)SEG)

// ---- prep Q/K: fp32 -> bf16 hi/lo, swizzled to A/B fragment order.
__global__ __launch_bounds__(256) void prep_qk(
    const float* __restrict__ Q, const float* __restrict__ K,
    char* __restrict__ ws)
{
    const int lane = threadIdx.x & 63;
    const int wv   = threadIdx.x >> 6;
    const int l15  = lane & 15;
    const int g    = lane >> 4;
    const int wid  = blockIdx.x * 4 + wv;          // 0..8191
    const int tensor = wid >> 12;
    const int rem  = wid & 4095;
    const int bh   = rem >> 7;
    const int blk  = rem & 127;

    const float* src = (tensor ? K : Q) + ((size_t)bh * S_SZ + blk * 16 + l15) * D_SZ;
    bf16x8* hi = (bf16x8*)(ws + (tensor ? KHI_OFF : QHI_OFF));
    bf16x8* lo = (bf16x8*)(ws + (tensor ? KLO_OFF : QLO_OFF));

    #pragma unroll
    for (int ks = 0; ks < 2; ++ks) {
        const float* p = src + 32 * ks + 8 * g;
        f32x4 a = *(const f32x4*)p;
        f32x4 b = *(const f32x4*)(p + 4);
        bf16x8 vh, vl;
        #pragma unroll
        for (int j = 0; j < 4; ++j) {
            __bf16 h0 = (__bf16)a[j];
            __bf16 h1 = (__bf16)b[j];
            vh[j]     = h0;
            vh[4 + j] = h1;
            vl[j]     = (__bf16)(a[j] - (float)h0);
            vl[4 + j] = (__bf16)(b[j] - (float)h1);
        }
        size_t di = ((size_t)(bh * NQB + blk) * 2 + ks) * 64 + lane;
        hi[di] = vh;
        lo[di] = vl;
    }
}

// ---- prep V: fp32 -> bf16, B-fragment order with pi-permutation baked in.
__global__ __launch_bounds__(256) void prep_v(
    const float* __restrict__ V, char* __restrict__ ws)
{
    __shared__ float vt[4][32 * 68];
    const int lane = threadIdx.x & 63;
    const int wv   = threadIdx.x >> 6;
    const int l15  = lane & 15;
    const int g    = lane >> 4;
    const int wid  = blockIdx.x * 4 + wv;          // 0..2047
    const int bh   = wid >> 6;
    const int u    = wid & 63;

    const float* src = V + ((size_t)bh * S_SZ + u * 32) * D_SZ;
    float* t = vt[wv];
    #pragma unroll
    for (int i = 0; i < 8; ++i) {
        int idx = i * 64 + lane;
        int row = idx >> 4;
        int c4  = idx & 15;
        *(f32x4*)(t + row * 68 + c4 * 4) = *(const f32x4*)(src + row * 64 + c4 * 4);
    }
    __syncthreads();

    bf16x8* vsw = (bf16x8*)(ws + VSW_OFF);
    #pragma unroll
    for (int db = 0; db < 4; ++db) {
        bf16x8 vb;
        #pragma unroll
        for (int j = 0; j < 8; ++j) {
            int kk = (j < 4) ? (4 * g + j) : (16 + 4 * g + (j - 4));
            vb[j] = (__bf16)t[kk * 68 + 16 * db + l15];
        }
        vsw[((size_t)(bh * NUB + u) * 4 + db) * 64 + lane] = vb;
    }
}

// ---- main fused kernel.
// __launch_bounds__(512,4): cap unified VGPR+AGPR at 128 -> 2 workgroups/CU.
__global__ __launch_bounds__(512, 4) void attn_fused2(
    const char* __restrict__ ws, float* __restrict__ OutC, float* __restrict__ OutW)
{
    __shared__ float redm[WAVES][QT];
    __shared__ float reds[WAVES][QT];
    __shared__ float ctxred[WAVES][QT][D_SZ];

    const int tid  = threadIdx.x;
    const int lane = tid & 63;
    const int wv   = tid >> 6;
    const int l15  = lane & 15;
    const int g    = lane >> 4;

    // XCD-aware swizzle: XCD x gets bh range [4x,4x+4) -> fragments stay in its L2
    const int b    = blockIdx.x;
    const int work = (b & 7) * 512 + (b >> 3);
    const int bh   = work >> 7;
    const int qt   = work & 127;
    const int q0   = qt * QT;

    const bf16x8* QHI = (const bf16x8*)(ws + QHI_OFF);
    const bf16x8* QLO = (const bf16x8*)(ws + QLO_OFF);
    const bf16x8* KHI = (const bf16x8*)(ws + KHI_OFF);
    const bf16x8* KLO = (const bf16x8*)(ws + KLO_OFF);
    const bf16x8* VSW = (const bf16x8*)(ws + VSW_OFF);

    float* Wb = OutW + (size_t)bh * S_SZ * S_SZ;
    float* Cb = OutC + (size_t)bh * S_SZ * D_SZ;

    // Q fragments
    bf16x8 qhi[2], qlo[2];
    {
        size_t qi = ((size_t)(bh * NQB + qt) * 2) * 64 + lane;
        qhi[0] = QHI[qi];       qhi[1] = QHI[qi + 64];
        qlo[0] = QLO[qi];       qlo[1] = QLO[qi + 64];
    }

    // QK^T: 16 col-blocks per wave, 6 MFMA each (3-term bf16 split)
    f32x4 s[16];
    const int kb0 = wv * 16;
    #pragma unroll
    for (int cb = 0; cb < 16; ++cb) {
        size_t bi = ((size_t)(bh * NQB + kb0 + cb) * 2) * 64 + lane;
        bf16x8 kh0 = KHI[bi], kh1 = KHI[bi + 64];
        bf16x8 kl0 = KLO[bi], kl1 = KLO[bi + 64];
        f32x4 acc = {0.f, 0.f, 0.f, 0.f};
        acc = __builtin_amdgcn_mfma_f32_16x16x32_bf16(kh0, qhi[0], acc, 0, 0, 0);
        acc = __builtin_amdgcn_mfma_f32_16x16x32_bf16(kh0, qlo[0], acc, 0, 0, 0);
        acc = __builtin_amdgcn_mfma_f32_16x16x32_bf16(kl0, qhi[0], acc, 0, 0, 0);
        acc = __builtin_amdgcn_mfma_f32_16x16x32_bf16(kh1, qhi[1], acc, 0, 0, 0);
        acc = __builtin_amdgcn_mfma_f32_16x16x32_bf16(kh1, qlo[1], acc, 0, 0, 0);
        acc = __builtin_amdgcn_mfma_f32_16x16x32_bf16(kl1, qhi[1], acc, 0, 0, 0);
        s[cb] = acc;
    }

    // row max
    float m = -3.0e38f;
    #pragma unroll
    for (int cb = 0; cb < 16; ++cb) {
        #pragma unroll
        for (int r = 0; r < 4; ++r) m = fmaxf(m, s[cb][r]);
    }
    m = fmaxf(m, __shfl_xor(m, 16));
    m = fmaxf(m, __shfl_xor(m, 32));
    if (lane < 16) redm[wv][l15] = m;
    __syncthreads();
    float mall = redm[0][l15];
    #pragma unroll
    for (int w2 = 1; w2 < WAVES; ++w2) mall = fmaxf(mall, redm[w2][l15]);

    // exp + row sum
    float sm = 0.f;
    #pragma unroll
    for (int cb = 0; cb < 16; ++cb) {
        #pragma unroll
        for (int r = 0; r < 4; ++r) {
            float e = __expf(s[cb][r] - mall);
            s[cb][r] = e;
            sm += e;
        }
    }
    sm += __shfl_xor(sm, 16);
    sm += __shfl_xor(sm, 32);
    if (lane < 16) reds[wv][l15] = sm;
    __syncthreads();
    float lsum = 0.f;
    #pragma unroll
    for (int w2 = 0; w2 < WAVES; ++w2) lsum += reds[w2][l15];
    const float inv = 1.0f / lsum;

    // normalize + nontemporal weight stores (write-once stream, keep out of L2)
    float* wrow = Wb + (size_t)(q0 + l15) * S_SZ + wv * 256;
    #pragma unroll
    for (int cb = 0; cb < 16; ++cb) {
        f32x4 wvec;
        #pragma unroll
        for (int r = 0; r < 4; ++r) wvec[r] = s[cb][r] * inv;
        s[cb] = wvec;
        __builtin_nontemporal_store(wvec, (f32x4*)(wrow + cb * 16 + 4 * g));
    }

    // PV: A = P direct from s[], B = pre-permuted V fragments
    f32x4 ctx[4];
    #pragma unroll
    for (int db = 0; db < 4; ++db) ctx[db] = (f32x4){0.f, 0.f, 0.f, 0.f};

    #pragma unroll
    for (int u = 0; u < 8; ++u) {
        bf16x8 pa;
        #pragma unroll
        for (int r = 0; r < 4; ++r) {
            pa[r]     = (__bf16)s[2 * u][r];
            pa[4 + r] = (__bf16)s[2 * u + 1][r];
        }
        size_t vbase = ((size_t)(bh * NUB + wv * 8 + u) * 4) * 64 + lane;
        #pragma unroll
        for (int db = 0; db < 4; ++db) {
            bf16x8 vb = VSW[vbase + (size_t)db * 64];
            ctx[db] = __builtin_amdgcn_mfma_f32_16x16x32_bf16(pa, vb, ctx[db], 0, 0, 0);
        }
    }

    // cross-wave context reduction
    #pragma unroll
    for (int db = 0; db < 4; ++db) {
        #pragma unroll
        for (int r = 0; r < 4; ++r)
            ctxred[wv][4 * g + r][16 * db + l15] = ctx[db][r];
    }
    __syncthreads();
    {
        const int qr = tid >> 6;
        const int d  = tid & 63;
        float acc0 = 0.f, acc1 = 0.f;
        #pragma unroll
        for (int w2 = 0; w2 < WAVES; ++w2) {
            acc0 += ctxred[w2][qr][d];
            acc1 += ctxred[w2][qr + 8][d];
        }
        __builtin_nontemporal_store(acc0, Cb + (size_t)(q0 + qr) * D_SZ + d);
        __builtin_nontemporal_store(acc1, Cb + (size_t)(q0 + qr + 8) * D_SZ + d);
    }
}

extern "C" void kernel_launch(void* const* d_in, const int* in_sizes, int n_in,
                              void* d_out, int out_size, void* d_ws, size_t ws_size,
                              hipStream_t stream)
{
    const float* Q = (const float*)d_in[0];
    const float* K = (const float*)d_in[1];
    const float* V = (const float*)d_in[2];
    float* ctx = (float*)d_out;
    float* w   = (float*)d_out + (size_t)B_SZ * H_SZ * S_SZ * D_SZ;
    char*  ws  = (char*)d_ws;

    prep_qk<<<2048, 256, 0, stream>>>(Q, K, ws);
    prep_v <<<512,  256, 0, stream>>>(V, ws);
    attn_fused2<<<4096, 512, 0, stream>>>(ws, ctx, w);
}

// Round 4
// 209.380 us; speedup vs baseline: 3.4929x; 1.0457x over previous
//
#include <hip/hip_runtime.h>
#include <hip/hip_bf16.h>

#define B_SZ 2
#define H_SZ 16
#define S_SZ 2048
#define D_SZ 64
#define QT   16
#define WAVES 8
#define NBH  (B_SZ * H_SZ)      // 32
#define NQB  (S_SZ / 16)        // 128 16-row blocks
#define NUB  (S_SZ / 32)        // 64 32-row V blocks

typedef __bf16 bf16x8 __attribute__((ext_vector_type(8)));
typedef float  f32x4  __attribute__((ext_vector_type(4)));

// d_ws layout: pre-swizzled bf16 MFMA fragments (8 MB segments)
#define SEG   (8u * 1024u * 1024u)
#define QHI_OFF (0 * (size_t)SEG)
#define QLO_OFF (1 * (size_t)SEG)
#define KHI_OFF (2 * (size_t)SEG)
#define KLO_OFF (3 * (size_t)SEG)
#define VSW_OFF (4 * (size_t)SEG)

// ---- prep Q/K: fp32 -> bf16 hi/lo, swizzled to A/B fragment order.
__global__ __launch_bounds__(256) void prep_qk(
    const float* __restrict__ Q, const float* __restrict__ K,
    char* __restrict__ ws)
{
    const int lane = threadIdx.x & 63;
    const int wv   = threadIdx.x >> 6;
    const int l15  = lane & 15;
    const int g    = lane >> 4;
    const int wid  = blockIdx.x * 4 + wv;          // 0..8191
    const int tensor = wid >> 12;
    const int rem  = wid & 4095;
    const int bh   = rem >> 7;
    const int blk  = rem & 127;

    const float* src = (tensor ? K : Q) + ((size_t)bh * S_SZ + blk * 16 + l15) * D_SZ;
    bf16x8* hi = (bf16x8*)(ws + (tensor ? KHI_OFF : QHI_OFF));
    bf16x8* lo = (bf16x8*)(ws + (tensor ? KLO_OFF : QLO_OFF));

    #pragma unroll
    for (int ks = 0; ks < 2; ++ks) {
        const float* p = src + 32 * ks + 8 * g;
        f32x4 a = *(const f32x4*)p;
        f32x4 b = *(const f32x4*)(p + 4);
        bf16x8 vh, vl;
        #pragma unroll
        for (int j = 0; j < 4; ++j) {
            __bf16 h0 = (__bf16)a[j];
            __bf16 h1 = (__bf16)b[j];
            vh[j]     = h0;
            vh[4 + j] = h1;
            vl[j]     = (__bf16)(a[j] - (float)h0);
            vl[4 + j] = (__bf16)(b[j] - (float)h1);
        }
        size_t di = ((size_t)(bh * NQB + blk) * 2 + ks) * 64 + lane;
        hi[di] = vh;
        lo[di] = vl;
    }
}

// ---- prep V: fp32 -> bf16, B-fragment order with pi-permutation baked in.
__global__ __launch_bounds__(256) void prep_v(
    const float* __restrict__ V, char* __restrict__ ws)
{
    __shared__ float vt[4][32 * 68];
    const int lane = threadIdx.x & 63;
    const int wv   = threadIdx.x >> 6;
    const int l15  = lane & 15;
    const int g    = lane >> 4;
    const int wid  = blockIdx.x * 4 + wv;          // 0..2047
    const int bh   = wid >> 6;
    const int u    = wid & 63;

    const float* src = V + ((size_t)bh * S_SZ + u * 32) * D_SZ;
    float* t = vt[wv];
    #pragma unroll
    for (int i = 0; i < 8; ++i) {
        int idx = i * 64 + lane;
        int row = idx >> 4;
        int c4  = idx & 15;
        *(f32x4*)(t + row * 68 + c4 * 4) = *(const f32x4*)(src + row * 64 + c4 * 4);
    }
    __syncthreads();

    bf16x8* vsw = (bf16x8*)(ws + VSW_OFF);
    #pragma unroll
    for (int db = 0; db < 4; ++db) {
        bf16x8 vb;
        #pragma unroll
        for (int j = 0; j < 8; ++j) {
            int kk = (j < 4) ? (4 * g + j) : (16 + 4 * g + (j - 4));
            vb[j] = (__bf16)t[kk * 68 + 16 * db + l15];
        }
        vsw[((size_t)(bh * NUB + u) * 4 + db) * 64 + lane] = vb;
    }
}

// ---- main fused kernel.
// Register discipline: s[16] (64 acc regs) is freed BEFORE PV by fusing
// normalize -> NT-store -> bf16 pack into one pass. Peak ~114 unified regs
// -> 4 waves/SIMD -> 2 workgroups/CU resident (cross-wg phase overlap).
__global__ __launch_bounds__(512, 4) void attn_fused2(
    const char* __restrict__ ws, float* __restrict__ OutC, float* __restrict__ OutW)
{
    __shared__ float redm[WAVES][QT];
    __shared__ float reds[WAVES][QT];
    __shared__ float ctxred[WAVES][QT][D_SZ];

    const int tid  = threadIdx.x;
    const int lane = tid & 63;
    const int wv   = tid >> 6;
    const int l15  = lane & 15;
    const int g    = lane >> 4;

    // XCD-aware swizzle: XCD x owns bh range [4x, 4x+4)
    const int b    = blockIdx.x;
    const int work = (b & 7) * 512 + (b >> 3);
    const int bh   = work >> 7;
    const int qt   = work & 127;
    const int q0   = qt * QT;

    const bf16x8* QHI = (const bf16x8*)(ws + QHI_OFF);
    const bf16x8* QLO = (const bf16x8*)(ws + QLO_OFF);
    const bf16x8* KHI = (const bf16x8*)(ws + KHI_OFF);
    const bf16x8* KLO = (const bf16x8*)(ws + KLO_OFF);
    const bf16x8* VSW = (const bf16x8*)(ws + VSW_OFF);

    float* Wb = OutW + (size_t)bh * S_SZ * S_SZ;
    float* Cb = OutC + (size_t)bh * S_SZ * D_SZ;

    // Q fragments
    bf16x8 qhi[2], qlo[2];
    {
        size_t qi = ((size_t)(bh * NQB + qt) * 2) * 64 + lane;
        qhi[0] = QHI[qi];       qhi[1] = QHI[qi + 64];
        qlo[0] = QLO[qi];       qlo[1] = QLO[qi + 64];
    }

    // QK^T: 16 col-blocks per wave, 6 MFMA each (3-term bf16 split)
    f32x4 s[16];
    const int kb0 = wv * 16;
    #pragma unroll
    for (int cb = 0; cb < 16; ++cb) {
        size_t bi = ((size_t)(bh * NQB + kb0 + cb) * 2) * 64 + lane;
        bf16x8 kh0 = KHI[bi], kh1 = KHI[bi + 64];
        bf16x8 kl0 = KLO[bi], kl1 = KLO[bi + 64];
        f32x4 acc = {0.f, 0.f, 0.f, 0.f};
        acc = __builtin_amdgcn_mfma_f32_16x16x32_bf16(kh0, qhi[0], acc, 0, 0, 0);
        acc = __builtin_amdgcn_mfma_f32_16x16x32_bf16(kh0, qlo[0], acc, 0, 0, 0);
        acc = __builtin_amdgcn_mfma_f32_16x16x32_bf16(kl0, qhi[0], acc, 0, 0, 0);
        acc = __builtin_amdgcn_mfma_f32_16x16x32_bf16(kh1, qhi[1], acc, 0, 0, 0);
        acc = __builtin_amdgcn_mfma_f32_16x16x32_bf16(kh1, qlo[1], acc, 0, 0, 0);
        acc = __builtin_amdgcn_mfma_f32_16x16x32_bf16(kl1, qhi[1], acc, 0, 0, 0);
        s[cb] = acc;
    }

    // row max
    float m = -3.0e38f;
    #pragma unroll
    for (int cb = 0; cb < 16; ++cb) {
        #pragma unroll
        for (int r = 0; r < 4; ++r) m = fmaxf(m, s[cb][r]);
    }
    m = fmaxf(m, __shfl_xor(m, 16));
    m = fmaxf(m, __shfl_xor(m, 32));
    if (lane < 16) redm[wv][l15] = m;
    __syncthreads();
    float mall = redm[0][l15];
    #pragma unroll
    for (int w2 = 1; w2 < WAVES; ++w2) mall = fmaxf(mall, redm[w2][l15]);

    // exp + row sum
    float sm = 0.f;
    #pragma unroll
    for (int cb = 0; cb < 16; ++cb) {
        #pragma unroll
        for (int r = 0; r < 4; ++r) {
            float e = __expf(s[cb][r] - mall);
            s[cb][r] = e;
            sm += e;
        }
    }
    sm += __shfl_xor(sm, 16);
    sm += __shfl_xor(sm, 32);
    if (lane < 16) reds[wv][l15] = sm;
    __syncthreads();
    float lsum = 0.f;
    #pragma unroll
    for (int w2 = 0; w2 < WAVES; ++w2) lsum += reds[w2][l15];
    const float inv = 1.0f / lsum;

    // fused: normalize -> NT store W -> pack P to bf16 (frees s[] before PV)
    bf16x8 pa[8];
    float* wrow = Wb + (size_t)(q0 + l15) * S_SZ + wv * 256;
    #pragma unroll
    for (int u = 0; u < 8; ++u) {
        f32x4 w0, w1;
        #pragma unroll
        for (int r = 0; r < 4; ++r) {
            w0[r] = s[2 * u][r] * inv;
            w1[r] = s[2 * u + 1][r] * inv;
        }
        __builtin_nontemporal_store(w0, (f32x4*)(wrow + (2 * u) * 16 + 4 * g));
        __builtin_nontemporal_store(w1, (f32x4*)(wrow + (2 * u + 1) * 16 + 4 * g));
        #pragma unroll
        for (int r = 0; r < 4; ++r) {
            pa[u][r]     = (__bf16)w0[r];
            pa[u][4 + r] = (__bf16)w1[r];
        }
    }

    // PV: A = packed P, B = pre-permuted V fragments
    f32x4 ctx[4];
    #pragma unroll
    for (int db = 0; db < 4; ++db) ctx[db] = (f32x4){0.f, 0.f, 0.f, 0.f};

    #pragma unroll
    for (int u = 0; u < 8; ++u) {
        size_t vbase = ((size_t)(bh * NUB + wv * 8 + u) * 4) * 64 + lane;
        #pragma unroll
        for (int db = 0; db < 4; ++db) {
            bf16x8 vb = VSW[vbase + (size_t)db * 64];
            ctx[db] = __builtin_amdgcn_mfma_f32_16x16x32_bf16(pa[u], vb, ctx[db], 0, 0, 0);
        }
    }

    // cross-wave context reduction
    #pragma unroll
    for (int db = 0; db < 4; ++db) {
        #pragma unroll
        for (int r = 0; r < 4; ++r)
            ctxred[wv][4 * g + r][16 * db + l15] = ctx[db][r];
    }
    __syncthreads();
    {
        const int qr = tid >> 6;
        const int d  = tid & 63;
        float acc0 = 0.f, acc1 = 0.f;
        #pragma unroll
        for (int w2 = 0; w2 < WAVES; ++w2) {
            acc0 += ctxred[w2][qr][d];
            acc1 += ctxred[w2][qr + 8][d];
        }
        __builtin_nontemporal_store(acc0, Cb + (size_t)(q0 + qr) * D_SZ + d);
        __builtin_nontemporal_store(acc1, Cb + (size_t)(q0 + qr + 8) * D_SZ + d);
    }
}

extern "C" void kernel_launch(void* const* d_in, const int* in_sizes, int n_in,
                              void* d_out, int out_size, void* d_ws, size_t ws_size,
                              hipStream_t stream)
{
    const float* Q = (const float*)d_in[0];
    const float* K = (const float*)d_in[1];
    const float* V = (const float*)d_in[2];
    float* ctx = (float*)d_out;
    float* w   = (float*)d_out + (size_t)B_SZ * H_SZ * S_SZ * D_SZ;
    char*  ws  = (char*)d_ws;

    prep_qk<<<2048, 256, 0, stream>>>(Q, K, ws);
    prep_v <<<512,  256, 0, stream>>>(V, ws);
    attn_fused2<<<4096, 512, 0, stream>>>(ws, ctx, w);
}